// Round 4
// baseline (434.971 us; speedup 1.0000x reference)
//
#include <hip/hip_runtime.h>
#include <hip/hip_bf16.h>

// B=4, H=16, S=2048, D=64
//   S = mask ? -1e9 : QK^T/8 ; O = S@V ; out = log_softmax(O, dim=-1)
// v9: v8's inline-asm v_cvt_pk_bf16_f32 caused loop-carried spills
// (WRITE_SIZE 33->352MB, attn 123->270us) — the guide's m240 warning.
// Same idea, sanctioned path: __float22bfloat162_rn builtin (compiler
// lowers to packed cvt, no opaque asm, regalloc intact). Keeps v7's
// register-transpose structure, 128-row q-tiles (4 blocks/CU), setprio
// around the MFMA cluster, and v8's sequential mask_pack.

typedef __attribute__((ext_vector_type(8))) short bf16x8;
typedef __attribute__((ext_vector_type(16))) float f32x16;

#define NEGV (-1e9f)

__device__ inline unsigned pk_rn(float a, float b) {    // packed RNE cvt (builtin)
    union { __hip_bfloat162 h; unsigned u; } t;
    t.h = __float22bfloat162_rn(float2{a, b});          // a -> low, b -> high
    return t.u;
}
__device__ inline unsigned pk_trunc(float a, float b) { // 1 v_perm_b32
    return __builtin_amdgcn_perm(__builtin_bit_cast(unsigned, b),
                                 __builtin_bit_cast(unsigned, a), 0x07060302u);
}

// ---- pre-kernel: mask int32 [b][q][kk] -> bit-words bitT[b][qt][ki][q] ----
// one q-row (8KB, fully sequential) per wave; 8192 rows = 8192 waves.
__global__ __launch_bounds__(256)
void mask_pack(const int* __restrict__ M, unsigned long long* __restrict__ bitT) {
    const int lane = threadIdx.x & 63;
    const int gw   = (blockIdx.x * 256 + threadIdx.x) >> 6;   // row id, 0..8191
    const int b    = gw >> 11;
    const int qt   = (gw >> 8) & 7;
    const int q    = gw & 255;
    const size_t mbase = (size_t)gw * 2048;
    unsigned long long* dst = bitT + (size_t)(b * 8 + qt) * 32 * 256 + q;
#pragma unroll 4
    for (int ki = 0; ki < 32; ki++) {
        const int m = M[mbase + ki * 64 + lane];
        const unsigned long long bal = __ballot(m != 0);
        if (lane == 0) dst[ki * 256] = bal;
    }
}

__global__ __launch_bounds__(256, 4)
void attn_kernel(const float* __restrict__ Q, const float* __restrict__ K,
                 const float* __restrict__ V,
                 const unsigned long long* __restrict__ bitT,
                 float* __restrict__ Out) {
    // pitch 72 shorts (36 dwords, 36 mod 32 = 4): bank-floor patterns.
    __shared__ __attribute__((aligned(16))) unsigned short sK[2][64 * 72];     // 18.4 KB dbuf
    __shared__ __attribute__((aligned(16))) unsigned short sVt[2][64 * 72];    // 18.4 KB dbuf (V^T)
    // total 36.9 KB -> 4 blocks/CU fits LDS (147.6/160 KB)

    const int tid  = threadIdx.x;
    const int wave = tid >> 6;
    const int lane = tid & 63;
    const int half = lane >> 5;
    const int l32  = lane & 31;

    const int bid = blockIdx.x;
    const int h   = bid & 15;            // 16 consecutive blocks share a mask tile
    const int qt2 = (bid >> 4) & 15;     // 128-row q-tile index
    const int b   = bid >> 8;
    const int bh  = b * 16 + h;
    const int q0  = qt2 * 128;
    const int qt  = qt2 >> 1;            // 256-row mask-tile index
    const int qh  = qt2 & 1;

    const float* Qb = Q + (size_t)(bh * 2048 + q0) * 64;
    const float* Kb = K + (size_t)bh * 2048 * 64;
    const float* Vb = V + (size_t)bh * 2048 * 64;
    // word for this lane's q-row (q = wave*32 + l32), same for both halves
    const unsigned long long* Bt = bitT + (size_t)(b * 8 + qt) * 32 * 256
                                 + qh * 128 + wave * 32 + l32;

    // ---- prologue: prefetch K/V/mask tile 0 into registers ----
    float4 kp[4];
    float  vp[16];
    unsigned long long mw = Bt[0];
    const int krow = tid >> 4, kc4 = tid & 15;
#pragma unroll
    for (int i = 0; i < 4; i++)
        kp[i] = *(const float4*)(Kb + (size_t)(krow + i * 16) * 64 + kc4 * 4);
#pragma unroll
    for (int i = 0; i < 2; i++) {
        const int kb = (wave * 2 + i) * 8;
#pragma unroll
        for (int j = 0; j < 8; j++)
            vp[i * 8 + j] = Vb[(size_t)(kb + j) * 64 + lane];
    }

    // ---- Q fragments direct from global (pre-scaled by 1/8), RNE, live all kernel ----
    bf16x8 qF[4];
    {
        const float* qr = Qb + (size_t)(wave * 32 + l32) * 64 + half * 8;
#pragma unroll
        for (int dk = 0; dk < 4; dk++) {
            const float4 f0 = *(const float4*)(qr + dk * 16);
            const float4 f1 = *(const float4*)(qr + dk * 16 + 4);
            union { bf16x8 v; unsigned u[4]; } t;
            t.u[0] = pk_rn(f0.x * 0.125f, f0.y * 0.125f);
            t.u[1] = pk_rn(f0.z * 0.125f, f0.w * 0.125f);
            t.u[2] = pk_rn(f1.x * 0.125f, f1.y * 0.125f);
            t.u[3] = pk_rn(f1.z * 0.125f, f1.w * 0.125f);
            qF[dk] = t.v;
        }
    }

    f32x16 Oacc[2];
#pragma unroll
    for (int db = 0; db < 2; db++)
#pragma unroll
        for (int r = 0; r < 16; r++) Oacc[db][r] = 0.f;

    for (int ki = 0; ki < 32; ki++) {
        const int cur = ki & 1;

        // ---- write prefetched tile ki into LDS[cur] ----
#pragma unroll
        for (int i = 0; i < 4; i++) {
            uint2 p;
            p.x = pk_trunc(kp[i].x, kp[i].y);
            p.y = pk_trunc(kp[i].z, kp[i].w);
            *(uint2*)&sK[cur][(krow + i * 16) * 72 + kc4 * 4] = p;
        }
#pragma unroll
        for (int i = 0; i < 2; i++) {
            const int kb = (wave * 2 + i) * 8;
            uint4 p4;
            p4.x = pk_rn(vp[i * 8 + 0], vp[i * 8 + 1]);
            p4.y = pk_rn(vp[i * 8 + 2], vp[i * 8 + 3]);
            p4.z = pk_rn(vp[i * 8 + 4], vp[i * 8 + 5]);
            p4.w = pk_rn(vp[i * 8 + 6], vp[i * 8 + 7]);
            *(uint4*)&sVt[cur][lane * 72 + kb] = p4;
        }

        __syncthreads();   // drain hits nothing in flight (all loads consumed)

        // ---- AFTER the barrier: issue next tile's prefetch (consumed before
        //      the next barrier -> never drained) ----
        unsigned long long mwN = 0;
        if (ki < 31) {
            const int kn = (ki + 1) * 64;
            mwN = Bt[(ki + 1) * 256];
#pragma unroll
            for (int i = 0; i < 4; i++)
                kp[i] = *(const float4*)(Kb + (size_t)(kn + krow + i * 16) * 64 + kc4 * 4);
#pragma unroll
            for (int i = 0; i < 2; i++) {
                const int kb = (wave * 2 + i) * 8;
#pragma unroll
                for (int j = 0; j < 8; j++)
                    vp[i * 8 + j] = Vb[(size_t)(kn + kb + j) * 64 + lane];
            }
        }

        // ---- per jk (32 kk rows): MFMA1 with mask-in-init, then in-register
        //      transpose (permlane32_swap) straight into MFMA2 ----
#pragma unroll
        for (int jk = 0; jk < 2; jk++) {
            bf16x8 aK[4];
#pragma unroll
            for (int dk = 0; dk < 4; dk++)
                aK[dk] = *(const bf16x8*)&sK[cur][(jk * 32 + l32) * 72 + dk * 16 + half * 8];
            bf16x8 bV[2][2];
#pragma unroll
            for (int p = 0; p < 2; p++)
#pragma unroll
                for (int db = 0; db < 2; db++)
                    bV[p][db] = *(const bf16x8*)&sVt[cur][(db * 32 + l32) * 72 + (jk * 2 + p) * 16 + half * 8];

            // bit for acc[rg*4+w] = jk*32 + rg*8 + half*4 + w  (q = l32's row word)
            const unsigned b32 = (unsigned)(mw >> (jk * 32));
            const unsigned bsh = b32 >> (half * 4);

            // masked init: -1e9 + qk trunc-packs to EXACTLY bf16(-1e9)
            // (f32 ulp at 2^29 = 64; trunc boundary absorbs +-1.7M >> |qk/8|)
            f32x16 acc;
#pragma unroll
            for (int rg = 0; rg < 4; rg++) {
                const unsigned nib = bsh >> (rg * 8);
                acc[rg * 4 + 0] = (nib & 1u) ? NEGV : 0.f;
                acc[rg * 4 + 1] = (nib & 2u) ? NEGV : 0.f;
                acc[rg * 4 + 2] = (nib & 4u) ? NEGV : 0.f;
                acc[rg * 4 + 3] = (nib & 8u) ? NEGV : 0.f;
            }

            __builtin_amdgcn_s_setprio(1);
#pragma unroll
            for (int dk = 0; dk < 4; dk++)
                acc = __builtin_amdgcn_mfma_f32_32x32x16_bf16(aK[dk], qF[dk], acc, 0, 0, 0);

            // acc[r] holds S[q=l32][kk32 = (r&3) + 8*(r>>2) + 4*half].
            // A-frag for kkb=2jk+p needs lane(half,l32): S[l32][p*16+half*8+j].
            // permlane32_swap(X,Y) -> ([X.row0|Y.row0], [X.row1|Y.row1]):
            //   (P0,P2) -> (word j=0,1 ; word j=4,5); (P1,P3) -> (j=2,3 ; j=6,7)
#pragma unroll
            for (int p = 0; p < 2; p++) {
                const unsigned P0 = pk_trunc(acc[p * 8 + 0], acc[p * 8 + 1]);
                const unsigned P1 = pk_trunc(acc[p * 8 + 2], acc[p * 8 + 3]);
                const unsigned P2 = pk_trunc(acc[p * 8 + 4], acc[p * 8 + 5]);
                const unsigned P3 = pk_trunc(acc[p * 8 + 6], acc[p * 8 + 7]);
                auto r02 = __builtin_amdgcn_permlane32_swap(P0, P2, false, false);
                auto r13 = __builtin_amdgcn_permlane32_swap(P1, P3, false, false);
                union { bf16x8 v; unsigned u[4]; } aS;
                aS.u[0] = (unsigned)r02[0];
                aS.u[1] = (unsigned)r13[0];
                aS.u[2] = (unsigned)r02[1];
                aS.u[3] = (unsigned)r13[1];
#pragma unroll
                for (int db = 0; db < 2; db++)
                    Oacc[db] = __builtin_amdgcn_mfma_f32_32x32x16_bf16(aS.v, bV[p][db], Oacc[db], 0, 0, 0);
            }
            __builtin_amdgcn_s_setprio(0);
        }

        mw = mwN;
    }

    // ---- epilogue: log_softmax over d=64 ----
    float* Ob = Out + (size_t)bh * 2048 * 64;
#pragma unroll
    for (int r = 0; r < 16; r++) {
        const float v0 = Oacc[0][r], v1 = Oacc[1][r];
        float mx = fmaxf(v0, v1);
#pragma unroll
        for (int off = 1; off < 32; off <<= 1)
            mx = fmaxf(mx, __shfl_xor(mx, off, 64));
        float s = __expf(v0 - mx) + __expf(v1 - mx);
#pragma unroll
        for (int off = 1; off < 32; off <<= 1)
            s += __shfl_xor(s, off, 64);
        const float lse = mx + __logf(s);
        const int qrow = q0 + wave * 32 + (r & 3) + 8 * (r >> 2) + 4 * half;
        Ob[(size_t)qrow * 64 + l32]      = v0 - lse;
        Ob[(size_t)qrow * 64 + 32 + l32] = v1 - lse;
    }
}

extern "C" void kernel_launch(void* const* d_in, const int* in_sizes, int n_in,
                              void* d_out, int out_size, void* d_ws, size_t ws_size,
                              hipStream_t stream) {
    const float* Q = (const float*)d_in[0];
    const float* K = (const float*)d_in[1];
    const float* V = (const float*)d_in[2];
    const int*   M = (const int*)d_in[3];
    float* Out = (float*)d_out;
    unsigned long long* bitT = (unsigned long long*)d_ws;   // needs 2 MB scratch

    mask_pack<<<dim3(2048), dim3(256), 0, stream>>>(M, bitT);
    attn_kernel<<<dim3(1024), dim3(256), 0, stream>>>(Q, K, V, bitT, Out);
}

// Round 5
// 261.509 us; speedup vs baseline: 1.6633x; 1.6633x over previous
//
#include <hip/hip_runtime.h>
#include <hip/hip_bf16.h>

// B=4, H=16, S=2048, D=64
//   S = mask ? -1e9 : QK^T/8 ; O = S@V ; out = log_softmax(O, dim=-1)
// v10: v8/v9 spilled (WRITE 352/394MB) — at launch_bounds(256,4) the
// 128-reg unified budget is a cliff; both the asm cvt operand-pinning and
// setprio's code-motion restriction tipped regalloc into loop-carried
// spill of kp/vp. Revert to v7 exactly (known 123us, clean), with ONE
// pressure-REDUCING change: V-pack via pk_trunc (1 v_perm) instead of the
// ~9-op manual RNE chain (-64 VALU/iter; K already trunc, error budget
// dominated by bf16(-1e9) trunc anyway). No setprio, no asm cvt.

typedef __attribute__((ext_vector_type(8))) short bf16x8;
typedef __attribute__((ext_vector_type(16))) float f32x16;

#define NEGV (-1e9f)

__device__ inline unsigned cvt_bf16(float f) {
    unsigned u = __builtin_bit_cast(unsigned, f);
    u += 0x7FFFu + ((u >> 16) & 1u);   // RNE
    return u >> 16;
}
__device__ inline unsigned pk_bf16(float a, float b) {       // RNE pack (prologue only)
    return cvt_bf16(a) | (cvt_bf16(b) << 16);
}
__device__ inline unsigned pk_trunc(float a, float b) {      // 1 v_perm_b32
    return __builtin_amdgcn_perm(__builtin_bit_cast(unsigned, b),
                                 __builtin_bit_cast(unsigned, a), 0x07060302u);
}

// ---- pre-kernel: mask int32 [b][q][kk] -> bit-words bitT[b][qt][ki][q] ----
// one q-row (8KB, fully sequential) per wave; 8192 rows = 8192 waves.
__global__ __launch_bounds__(256)
void mask_pack(const int* __restrict__ M, unsigned long long* __restrict__ bitT) {
    const int lane = threadIdx.x & 63;
    const int gw   = (blockIdx.x * 256 + threadIdx.x) >> 6;   // row id, 0..8191
    const int b    = gw >> 11;
    const int qt   = (gw >> 8) & 7;
    const int q    = gw & 255;
    const size_t mbase = (size_t)gw * 2048;
    unsigned long long* dst = bitT + (size_t)(b * 8 + qt) * 32 * 256 + q;
#pragma unroll 4
    for (int ki = 0; ki < 32; ki++) {
        const int m = M[mbase + ki * 64 + lane];
        const unsigned long long bal = __ballot(m != 0);
        if (lane == 0) dst[ki * 256] = bal;
    }
}

__global__ __launch_bounds__(256, 4)
void attn_kernel(const float* __restrict__ Q, const float* __restrict__ K,
                 const float* __restrict__ V,
                 const unsigned long long* __restrict__ bitT,
                 float* __restrict__ Out) {
    // pitch 72 shorts (36 dwords, 36 mod 32 = 4): bank-floor patterns.
    __shared__ __attribute__((aligned(16))) unsigned short sK[2][64 * 72];     // 18.4 KB dbuf
    __shared__ __attribute__((aligned(16))) unsigned short sVt[2][64 * 72];    // 18.4 KB dbuf (V^T)
    // total 36.9 KB -> 4 blocks/CU fits LDS (147.6/160 KB)

    const int tid  = threadIdx.x;
    const int wave = tid >> 6;
    const int lane = tid & 63;
    const int half = lane >> 5;
    const int l32  = lane & 31;

    const int bid = blockIdx.x;
    const int h   = bid & 15;            // 16 consecutive blocks share a mask tile
    const int qt2 = (bid >> 4) & 15;     // 128-row q-tile index
    const int b   = bid >> 8;
    const int bh  = b * 16 + h;
    const int q0  = qt2 * 128;
    const int qt  = qt2 >> 1;            // 256-row mask-tile index
    const int qh  = qt2 & 1;

    const float* Qb = Q + (size_t)(bh * 2048 + q0) * 64;
    const float* Kb = K + (size_t)bh * 2048 * 64;
    const float* Vb = V + (size_t)bh * 2048 * 64;
    // word for this lane's q-row (q = wave*32 + l32), same for both halves
    const unsigned long long* Bt = bitT + (size_t)(b * 8 + qt) * 32 * 256
                                 + qh * 128 + wave * 32 + l32;

    // ---- prologue: prefetch K/V/mask tile 0 into registers ----
    float4 kp[4];
    float  vp[16];
    unsigned long long mw = Bt[0];
    const int krow = tid >> 4, kc4 = tid & 15;
#pragma unroll
    for (int i = 0; i < 4; i++)
        kp[i] = *(const float4*)(Kb + (size_t)(krow + i * 16) * 64 + kc4 * 4);
#pragma unroll
    for (int i = 0; i < 2; i++) {
        const int kb = (wave * 2 + i) * 8;
#pragma unroll
        for (int j = 0; j < 8; j++)
            vp[i * 8 + j] = Vb[(size_t)(kb + j) * 64 + lane];
    }

    // ---- Q fragments direct from global (pre-scaled by 1/8), RNE, live all kernel ----
    bf16x8 qF[4];
    {
        const float* qr = Qb + (size_t)(wave * 32 + l32) * 64 + half * 8;
#pragma unroll
        for (int dk = 0; dk < 4; dk++) {
            const float4 f0 = *(const float4*)(qr + dk * 16);
            const float4 f1 = *(const float4*)(qr + dk * 16 + 4);
            union { bf16x8 v; unsigned u[4]; } t;
            t.u[0] = pk_bf16(f0.x * 0.125f, f0.y * 0.125f);
            t.u[1] = pk_bf16(f0.z * 0.125f, f0.w * 0.125f);
            t.u[2] = pk_bf16(f1.x * 0.125f, f1.y * 0.125f);
            t.u[3] = pk_bf16(f1.z * 0.125f, f1.w * 0.125f);
            qF[dk] = t.v;
        }
    }

    f32x16 Oacc[2];
#pragma unroll
    for (int db = 0; db < 2; db++)
#pragma unroll
        for (int r = 0; r < 16; r++) Oacc[db][r] = 0.f;

    for (int ki = 0; ki < 32; ki++) {
        const int cur = ki & 1;

        // ---- write prefetched tile ki into LDS[cur] ----
#pragma unroll
        for (int i = 0; i < 4; i++) {
            uint2 p;
            p.x = pk_trunc(kp[i].x, kp[i].y);
            p.y = pk_trunc(kp[i].z, kp[i].w);
            *(uint2*)&sK[cur][(krow + i * 16) * 72 + kc4 * 4] = p;
        }
#pragma unroll
        for (int i = 0; i < 2; i++) {
            const int kb = (wave * 2 + i) * 8;
            uint4 p4;
            p4.x = pk_trunc(vp[i * 8 + 0], vp[i * 8 + 1]);
            p4.y = pk_trunc(vp[i * 8 + 2], vp[i * 8 + 3]);
            p4.z = pk_trunc(vp[i * 8 + 4], vp[i * 8 + 5]);
            p4.w = pk_trunc(vp[i * 8 + 6], vp[i * 8 + 7]);
            *(uint4*)&sVt[cur][lane * 72 + kb] = p4;
        }

        __syncthreads();   // drain hits nothing in flight (all loads consumed)

        // ---- AFTER the barrier: issue next tile's prefetch (consumed before
        //      the next barrier -> never drained) ----
        unsigned long long mwN = 0;
        if (ki < 31) {
            const int kn = (ki + 1) * 64;
            mwN = Bt[(ki + 1) * 256];
#pragma unroll
            for (int i = 0; i < 4; i++)
                kp[i] = *(const float4*)(Kb + (size_t)(kn + krow + i * 16) * 64 + kc4 * 4);
#pragma unroll
            for (int i = 0; i < 2; i++) {
                const int kb = (wave * 2 + i) * 8;
#pragma unroll
                for (int j = 0; j < 8; j++)
                    vp[i * 8 + j] = Vb[(size_t)(kn + kb + j) * 64 + lane];
            }
        }

        // ---- per jk (32 kk rows): MFMA1 with mask-in-init, then in-register
        //      transpose (permlane32_swap) straight into MFMA2 ----
#pragma unroll
        for (int jk = 0; jk < 2; jk++) {
            bf16x8 aK[4];
#pragma unroll
            for (int dk = 0; dk < 4; dk++)
                aK[dk] = *(const bf16x8*)&sK[cur][(jk * 32 + l32) * 72 + dk * 16 + half * 8];
            bf16x8 bV[2][2];
#pragma unroll
            for (int p = 0; p < 2; p++)
#pragma unroll
                for (int db = 0; db < 2; db++)
                    bV[p][db] = *(const bf16x8*)&sVt[cur][(db * 32 + l32) * 72 + (jk * 2 + p) * 16 + half * 8];

            // bit for acc[rg*4+w] = jk*32 + rg*8 + half*4 + w  (q = l32's row word)
            const unsigned b32 = (unsigned)(mw >> (jk * 32));
            const unsigned bsh = b32 >> (half * 4);

            // masked init: -1e9 + qk trunc-packs to EXACTLY bf16(-1e9)
            // (f32 ulp at 2^29 = 64; trunc boundary absorbs +-1.7M >> |qk/8|)
            f32x16 acc;
#pragma unroll
            for (int rg = 0; rg < 4; rg++) {
                const unsigned nib = bsh >> (rg * 8);
                acc[rg * 4 + 0] = (nib & 1u) ? NEGV : 0.f;
                acc[rg * 4 + 1] = (nib & 2u) ? NEGV : 0.f;
                acc[rg * 4 + 2] = (nib & 4u) ? NEGV : 0.f;
                acc[rg * 4 + 3] = (nib & 8u) ? NEGV : 0.f;
            }
#pragma unroll
            for (int dk = 0; dk < 4; dk++)
                acc = __builtin_amdgcn_mfma_f32_32x32x16_bf16(aK[dk], qF[dk], acc, 0, 0, 0);

            // acc[r] holds S[q=l32][kk32 = (r&3) + 8*(r>>2) + 4*half].
            // A-frag for kkb=2jk+p needs lane(half,l32): S[l32][p*16+half*8+j].
            // permlane32_swap(X,Y) -> ([X.row0|Y.row0], [X.row1|Y.row1]):
            //   (P0,P2) -> (word j=0,1 ; word j=4,5); (P1,P3) -> (j=2,3 ; j=6,7)
#pragma unroll
            for (int p = 0; p < 2; p++) {
                const unsigned P0 = pk_trunc(acc[p * 8 + 0], acc[p * 8 + 1]);
                const unsigned P1 = pk_trunc(acc[p * 8 + 2], acc[p * 8 + 3]);
                const unsigned P2 = pk_trunc(acc[p * 8 + 4], acc[p * 8 + 5]);
                const unsigned P3 = pk_trunc(acc[p * 8 + 6], acc[p * 8 + 7]);
                auto r02 = __builtin_amdgcn_permlane32_swap(P0, P2, false, false);
                auto r13 = __builtin_amdgcn_permlane32_swap(P1, P3, false, false);
                union { bf16x8 v; unsigned u[4]; } aS;
                aS.u[0] = (unsigned)r02[0];
                aS.u[1] = (unsigned)r13[0];
                aS.u[2] = (unsigned)r02[1];
                aS.u[3] = (unsigned)r13[1];
#pragma unroll
                for (int db = 0; db < 2; db++)
                    Oacc[db] = __builtin_amdgcn_mfma_f32_32x32x16_bf16(aS.v, bV[p][db], Oacc[db], 0, 0, 0);
            }
        }

        mw = mwN;
    }

    // ---- epilogue: log_softmax over d=64 ----
    float* Ob = Out + (size_t)bh * 2048 * 64;
#pragma unroll
    for (int r = 0; r < 16; r++) {
        const float v0 = Oacc[0][r], v1 = Oacc[1][r];
        float mx = fmaxf(v0, v1);
#pragma unroll
        for (int off = 1; off < 32; off <<= 1)
            mx = fmaxf(mx, __shfl_xor(mx, off, 64));
        float s = __expf(v0 - mx) + __expf(v1 - mx);
#pragma unroll
        for (int off = 1; off < 32; off <<= 1)
            s += __shfl_xor(s, off, 64);
        const float lse = mx + __logf(s);
        const int qrow = q0 + wave * 32 + (r & 3) + 8 * (r >> 2) + 4 * half;
        Ob[(size_t)qrow * 64 + l32]      = v0 - lse;
        Ob[(size_t)qrow * 64 + 32 + l32] = v1 - lse;
    }
}

extern "C" void kernel_launch(void* const* d_in, const int* in_sizes, int n_in,
                              void* d_out, int out_size, void* d_ws, size_t ws_size,
                              hipStream_t stream) {
    const float* Q = (const float*)d_in[0];
    const float* K = (const float*)d_in[1];
    const float* V = (const float*)d_in[2];
    const int*   M = (const int*)d_in[3];
    float* Out = (float*)d_out;
    unsigned long long* bitT = (unsigned long long*)d_ws;   // needs 2 MB scratch

    mask_pack<<<dim3(2048), dim3(256), 0, stream>>>(M, bitT);
    attn_kernel<<<dim3(1024), dim3(256), 0, stream>>>(Q, K, V, bitT, Out);
}